// Round 22
// baseline (105.637 us; speedup 1.0000x reference)
//
#include <hip/hip_runtime.h>

// MHA: B=4, S=2048, D_MODEL=512, H=8, D_HEAD=64
// prep (Wt transpose + QKV fp32->bf16) -> qkv GEMMs (gl_lds + XCD swizzle) ->
// flash attn (r22: r21 + depth-2 K/V prefetch, 3 buffers, counted vmcnt(2)
// end-of-tile wait -- load pairs are barrier/fence-separated so the count is
// issue-order-robust) -> out proj GEMM (swizzled).

typedef unsigned short u16;
typedef __bf16 bf16x8 __attribute__((ext_vector_type(8)));
typedef float  f32x4  __attribute__((ext_vector_type(4)));

__device__ __forceinline__ u16 f2bf(float x) {
  unsigned u = __float_as_uint(x);
  u += 0x7fffu + ((u >> 16) & 1u);   // RNE
  return (u16)(u >> 16);
}

__device__ __forceinline__ unsigned cvtpk(float lo, float hi) {
  unsigned r;
  asm("v_cvt_pk_bf16_f32 %0, %1, %2" : "=v"(r) : "v"(lo), "v"(hi));
  return r;
}

__device__ __forceinline__ f32x4 mfma16(bf16x8 a, bf16x8 b, f32x4 c) {
  return __builtin_amdgcn_mfma_f32_16x16x32_bf16(a, b, c, 0, 0, 0);
}

// async 16B/lane global->LDS; lds dest is wave-uniform base (HW adds lane*16)
__device__ __forceinline__ void gl16(const u16* g, u16* l) {
  __builtin_amdgcn_global_load_lds(
      (const __attribute__((address_space(1))) void*)g,
      (__attribute__((address_space(3))) void*)l, 16, 0, 0);
}

#define MX3(a, b, c) fmaxf(fmaxf((a), (b)), (c))

// ---- prep: Wt transpose (y=0..3) + Q/K/V fp32->bf16 convert (y=4..6) ----
__global__ __launch_bounds__(256) void prep_k(const float* __restrict__ W0,
                                              const float* __restrict__ W1,
                                              const float* __restrict__ W2,
                                              const float* __restrict__ W3,
                                              u16* __restrict__ Wt,
                                              const float* __restrict__ Q,
                                              const float* __restrict__ K,
                                              const float* __restrict__ V,
                                              u16* __restrict__ Oq,
                                              u16* __restrict__ Ok,
                                              u16* __restrict__ Ov) {
  int y = blockIdx.y;
  if (y < 4) {
    if (blockIdx.x >= 1024) return;
    const float* W = y == 0 ? W0 : y == 1 ? W1 : y == 2 ? W2 : W3;
    int idx = blockIdx.x * 256 + threadIdx.x;
    int k = idx >> 9, n = idx & 511;
    Wt[y * 262144 + n * 512 + k] = f2bf(W[idx]);
  } else {
    int sel = y - 4;
    const float* X = sel == 0 ? Q : sel == 1 ? K : V;
    u16* O = sel == 0 ? Oq : sel == 1 ? Ok : Ov;
    size_t i = ((size_t)blockIdx.x * 256 + threadIdx.x) * 8;
    float4 a = *(const float4*)(X + i);
    float4 b = *(const float4*)(X + i + 4);
    uint4 pk = make_uint4(cvtpk(a.x, a.y), cvtpk(a.z, a.w),
                          cvtpk(b.x, b.y), cvtpk(b.z, b.w));
    *(uint4*)(O + i) = pk;
  }
}

// ---- m97-style bf16 GEMM: A[8192x512] @ Bt^T + bias (Bt [n][k] bf16) ----
// OUT_MODE: 0 bf16 [m][n], 1 bf16 vT[(b*8+h)*64+d][s], 2 fp32 [m][n]
template <int OUT_MODE, int BN>
__device__ __forceinline__ void gemm_body(const u16* __restrict__ A,
                                          const u16* __restrict__ Bt,
                                          const float* __restrict__ bias,
                                          void* __restrict__ outp, int bidx) {
  constexpr int NF = BN / 32;
  constexpr int NBN = 512 / BN;
  __shared__ __align__(16) u16 As[128][64];
  __shared__ __align__(16) u16 Bs[BN][64];
  int tid = threadIdx.x;
  int lane = tid & 63, wid = tid >> 6;
  int wm = wid >> 1, wn = wid & 1;
  int lr = lane & 15, lg = lane >> 4;
  int bm = bidx / NBN, bn = bidx % NBN;

  int r0 = tid >> 3;
  int c8s = (tid & 7) ^ (r0 & 7);
  const u16* Ab = A + (size_t)(bm * 128) * 512;
  const u16* Bb = Bt + (size_t)(bn * BN) * 512;

  f32x4 acc[4][NF];
#pragma unroll
  for (int i = 0; i < 4; ++i)
#pragma unroll
    for (int j = 0; j < NF; ++j) {
      f32x4 z = {0.f, 0.f, 0.f, 0.f};
      acc[i][j] = z;
    }

#pragma unroll
  for (int kt = 0; kt < 8; ++kt) {
    int k0 = kt * 64;
#pragma unroll
    for (int i = 0; i < 4; ++i)
      gl16(&Ab[(size_t)(i * 32 + r0) * 512 + k0 + c8s * 8],
           &As[0][0] + i * 2048 + wid * 512);
#pragma unroll
    for (int i = 0; i < BN / 32; ++i)
      gl16(&Bb[(size_t)(i * 32 + r0) * 512 + k0 + c8s * 8],
           &Bs[0][0] + i * 2048 + wid * 512);
    __syncthreads();
#pragma unroll
    for (int kk = 0; kk < 2; ++kk) {
      bf16x8 af[4], bfr[NF];
      int sw = (lr & 7) << 3;
#pragma unroll
      for (int mf = 0; mf < 4; ++mf)
        af[mf] = *(const bf16x8*)&As[wm * 64 + mf * 16 + lr][(kk * 32 + lg * 8) ^ sw];
#pragma unroll
      for (int nf = 0; nf < NF; ++nf)
        bfr[nf] = *(const bf16x8*)&Bs[wn * (BN / 2) + nf * 16 + lr][(kk * 32 + lg * 8) ^ sw];
#pragma unroll
      for (int mf = 0; mf < 4; ++mf)
#pragma unroll
        for (int nf = 0; nf < NF; ++nf)
          acc[mf][nf] = mfma16(af[mf], bfr[nf], acc[mf][nf]);
    }
    __syncthreads();
  }

#pragma unroll
  for (int mf = 0; mf < 4; ++mf) {
#pragma unroll
    for (int nf = 0; nf < NF; ++nf) {
      int m = bm * 128 + wm * 64 + mf * 16 + lg * 4;
      int n = bn * BN + wn * (BN / 2) + nf * 16 + lr;
      float bia = bias[n];
      if (OUT_MODE == 0) {
        u16* o = (u16*)outp;
#pragma unroll
        for (int r = 0; r < 4; ++r)
          o[(size_t)(m + r) * 512 + n] = f2bf(acc[mf][nf][r] + bia);
      } else if (OUT_MODE == 2) {
        float* o = (float*)outp;
#pragma unroll
        for (int r = 0; r < 4; ++r)
          o[(size_t)(m + r) * 512 + n] = acc[mf][nf][r] + bia;
      } else {
        u16* o = (u16*)outp;
        int b = m >> 11, s = m & 2047;
        int h = n >> 6, d = n & 63;
        ushort4 pk = make_ushort4(f2bf(acc[mf][nf][0] + bia), f2bf(acc[mf][nf][1] + bia),
                                  f2bf(acc[mf][nf][2] + bia), f2bf(acc[mf][nf][3] + bia));
        *(ushort4*)&o[(size_t)((b * 8 + h) * 64 + d) * 2048 + s] = pk;
      }
    }
  }
}

__global__ __launch_bounds__(256) void qkv_k(const u16* __restrict__ Aq,
                                             const u16* __restrict__ Ak,
                                             const u16* __restrict__ Av,
                                             const u16* __restrict__ Wt,
                                             const float* __restrict__ bq,
                                             const float* __restrict__ bk,
                                             const float* __restrict__ bv,
                                             u16* __restrict__ outbase) {
  int sel = blockIdx.y;
  const u16* A = sel == 0 ? Aq : sel == 1 ? Ak : Av;
  const float* bia = sel == 0 ? bq : sel == 1 ? bk : bv;
  const u16* Bt = Wt + (size_t)sel * 262144;
  u16* out = outbase + (size_t)sel * 8192 * 512;
  int wg = blockIdx.x;
  int wgs = (wg & 7) * 32 + (wg >> 3);   // XCD swizzle (bijective)
  if (sel == 2)
    gemm_body<1, 128>(A, Bt, bia, out, wgs);
  else
    gemm_body<0, 128>(A, Bt, bia, out, wgs);
}

__global__ __launch_bounds__(256) void gemm_out_k(const u16* __restrict__ Ap,
                                                  const u16* __restrict__ Bt,
                                                  const float* __restrict__ bias,
                                                  void* __restrict__ outp) {
  int wg = blockIdx.x;
  int wgs = (wg & 7) * 64 + (wg >> 3);   // XCD swizzle (bijective)
  gemm_body<2, 64>(Ap, Bt, bias, outp, wgs);
}

// ---- flash attention r22: depth-2 prefetch, 3 K/V buffers, counted vmcnt ----
// 8 waves/block, QBLK=128, XCD swizzle. Load pair(t+2) issued at tile t;
// end-of-tile waits vmcnt(2) (= pair(t+1) done, pair(t+2) stays in flight).
// Pairs are separated by memory-clobber fences + barriers -> count is robust.
__global__ __launch_bounds__(512) void attn_k(const u16* __restrict__ q,
                                              const u16* __restrict__ kmat,
                                              const u16* __restrict__ vT,
                                              u16* __restrict__ z) {
  __shared__ __align__(16) u16 Ks[3][64][64];   // [buf][key][d], swizzled content
  __shared__ __align__(16) u16 Vs[3][64][64];   // [buf][d][key], swizzled content
  __shared__ __align__(16) u16 Ps[8][16][72];   // per-wave P[q][key]
  const float C = 0.125f * 1.44269504f;         // 1/sqrt(64) * log2(e)
  int tid = threadIdx.x;
  int lane = tid & 63, w = tid >> 6;            // w = 0..7
  int lr = lane & 15, lg = lane >> 4;
  // XCD swizzle (bijective, 512 % 8 == 0): XCD x owns 4 consecutive bh.
  int wg = blockIdx.x;
  int wgs = (wg & 7) * 64 + (wg >> 3);
  int bh = wgs >> 4, qt = wgs & 15;
  int b = bh >> 3, h = bh & 7;
  size_t qrow0 = (size_t)(b * 2048 + qt * 128 + w * 16);

  bf16x8 qf[2];
#pragma unroll
  for (int kf = 0; kf < 2; ++kf)
    qf[kf] = *(const bf16x8*)&q[(qrow0 + lr) * 512 + h * 64 + kf * 32 + lg * 8];

  f32x4 oacc[4];
#pragma unroll
  for (int j = 0; j < 4; ++j) {
    f32x4 zf = {0.f, 0.f, 0.f, 0.f};
    oacc[j] = zf;
  }
  float m = -1e30f, l_part = 0.f, negmC = 0.f;

  const u16* kbase = kmat + (size_t)(b * 2048) * 512 + h * 64;
  const u16* vbase = vT + (size_t)(bh * 64) * 2048;

  int r0 = tid >> 3;                         // 0..63 (512 threads cover 64 rows)
  int c8s = (tid & 7) ^ (r0 & 7);
  int sw = (lr & 7) << 3;                    // fragment-read swizzle (row&7 == lr&7)

  // prologue: pair(0) -> buf0, pair(1) -> buf1; wait pair(0) (vmcnt 2 = pair1
  // outstanding); publish.
  gl16(&kbase[(size_t)r0 * 512 + c8s * 8], &Ks[0][0][0] + w * 512);
  gl16(&vbase[(size_t)r0 * 2048 + c8s * 8], &Vs[0][0][0] + w * 512);
  gl16(&kbase[(size_t)(64 + r0) * 512 + c8s * 8], &Ks[1][0][0] + w * 512);
  gl16(&vbase[(size_t)r0 * 2048 + 64 + c8s * 8], &Vs[1][0][0] + w * 512);
  asm volatile("s_waitcnt vmcnt(2)" ::: "memory");
  __builtin_amdgcn_s_barrier();

  // one KV tile: compute on (Kc,Vc) = buf[kt%3]; issue pair(kt+2) -> (Kn,Vn).
  auto tile = [&](int kt, const u16* Kc, const u16* Vc, u16* Kn, u16* Vn) {
    if (kt < 30) {
      gl16(&kbase[(size_t)((kt + 2) * 64 + r0) * 512 + c8s * 8], Kn + w * 512);
      gl16(&vbase[(size_t)r0 * 2048 + (kt + 2) * 64 + c8s * 8], Vn + w * 512);
    }

    // S^T = K @ Q^T : sacc[nf][r] = S[q=lr][key = nf*16 + lg*4 + r]
    f32x4 sacc[4];
#pragma unroll
    for (int j = 0; j < 4; ++j) {
      f32x4 zf = {0.f, 0.f, 0.f, 0.f};
      sacc[j] = zf;
    }
#pragma unroll
    for (int kf = 0; kf < 2; ++kf) {
#pragma unroll
      for (int nf = 0; nf < 4; ++nf) {
        int row = nf * 16 + lr;
        bf16x8 kb = *(const bf16x8*)&Kc[row * 64 + ((kf * 32 + lg * 8) ^ sw)];
        sacc[nf] = mfma16(kb, qf[kf], sacc[nf]);
      }
    }

    // lane-local 16-value max via max3 triples (8 ops)
    float t0 = MX3(sacc[0][0], sacc[0][1], sacc[0][2]);
    float t1 = MX3(sacc[0][3], sacc[1][0], sacc[1][1]);
    float t2 = MX3(sacc[1][2], sacc[1][3], sacc[2][0]);
    float t3 = MX3(sacc[2][1], sacc[2][2], sacc[2][3]);
    float t4 = MX3(sacc[3][0], sacc[3][1], sacc[3][2]);
    float mxl = fmaxf(MX3(t0, t1, t2), MX3(t3, t4, sacc[3][3]));

    // defer-max: lane-local test exact; shuffles + rescale only in rare branch
    if (!__all(mxl - m <= 8.f)) {
      float mx = fmaxf(mxl, __shfl_xor(mxl, 16));
      mx = fmaxf(mx, __shfl_xor(mx, 32));
      float mnew = fmaxf(m, mx);
      float sc = __builtin_amdgcn_exp2f((m - mnew) * C);
      m = mnew;
      negmC = -m * C;
      l_part *= sc;
#pragma unroll
      for (int nfo = 0; nfo < 4; ++nfo)
#pragma unroll
        for (int r = 0; r < 4; ++r) oacc[nfo][r] *= sc;
    }

    // P = exp2(S*C - m*C); per-lane partial sum; pack to Ps
    float rsum = 0.f;
#pragma unroll
    for (int nf = 0; nf < 4; ++nf) {
      float p0 = __builtin_amdgcn_exp2f(fmaf(sacc[nf][0], C, negmC));
      float p1 = __builtin_amdgcn_exp2f(fmaf(sacc[nf][1], C, negmC));
      float p2 = __builtin_amdgcn_exp2f(fmaf(sacc[nf][2], C, negmC));
      float p3 = __builtin_amdgcn_exp2f(fmaf(sacc[nf][3], C, negmC));
      rsum += (p0 + p1) + (p2 + p3);
      uint2 pw = make_uint2(cvtpk(p0, p1), cvtpk(p2, p3));
      *(uint2*)&Ps[w][lr][nf * 16 + lg * 4] = pw;
    }
    l_part += rsum;

    // Ps write->read ordering (wave-private): proven fence pair.
    asm volatile("s_waitcnt lgkmcnt(0)" ::: "memory");
    __builtin_amdgcn_sched_barrier(0);

    // O^T += V^T @ P^T (V(kt) resident since the barrier that closed tile kt-1)
#pragma unroll
    for (int ks = 0; ks < 2; ++ks) {
      bf16x8 pa = *(const bf16x8*)&Ps[w][lr][ks * 32 + lg * 8];
#pragma unroll
      for (int nfo = 0; nfo < 4; ++nfo) {
        int row = nfo * 16 + lr;
        bf16x8 vbr = *(const bf16x8*)&Vc[row * 64 + ((ks * 32 + lg * 8) ^ sw)];
        oacc[nfo] = mfma16(vbr, pa, oacc[nfo]);
      }
    }

    // end-of-tile: wait pair(kt+1) only (counted; pair(kt+2) stays in flight),
    // drain LDS reads, publish. Raw s_barrier avoids compiler's full drain.
    asm volatile("s_waitcnt lgkmcnt(0)" ::: "memory");
    if (kt < 30) {
      asm volatile("s_waitcnt vmcnt(2)" ::: "memory");
    } else {
      asm volatile("s_waitcnt vmcnt(0)" ::: "memory");
    }
    __builtin_amdgcn_s_barrier();
  };

  u16* K0 = &Ks[0][0][0], *K1 = &Ks[1][0][0], *K2 = &Ks[2][0][0];
  u16* V0 = &Vs[0][0][0], *V1 = &Vs[1][0][0], *V2 = &Vs[2][0][0];
  for (int ko = 0; ko < 30; ko += 3) {
    tile(ko,     K0, V0, K2, V2);
    tile(ko + 1, K1, V1, K0, V0);
    tile(ko + 2, K2, V2, K1, V1);
  }
  tile(30, K0, V0, K2, V2);   // no issue (kt>=30), vmcnt(0) tail
  tile(31, K1, V1, K0, V0);

  // combine per-lane l partials once (row = lanes {lr, lr+16, lr+32, lr+48})
  float l = l_part + __shfl_xor(l_part, 16);
  l += __shfl_xor(l, 32);
  float rl = 1.f / l;
#pragma unroll
  for (int nfo = 0; nfo < 4; ++nfo) {
    uint2 pw = make_uint2(cvtpk(oacc[nfo][0] * rl, oacc[nfo][1] * rl),
                          cvtpk(oacc[nfo][2] * rl, oacc[nfo][3] * rl));
    *(uint2*)&z[(qrow0 + lr) * 512 + h * 64 + nfo * 16 + lg * 4] = pw;
  }
}

extern "C" void kernel_launch(void* const* d_in, const int* in_sizes, int n_in,
                              void* d_out, int out_size, void* d_ws, size_t ws_size,
                              hipStream_t stream) {
  const float* Q  = (const float*)d_in[0];
  const float* K  = (const float*)d_in[1];
  const float* V  = (const float*)d_in[2];
  const float* Wq = (const float*)d_in[3];
  const float* bq = (const float*)d_in[4];
  const float* Wk = (const float*)d_in[5];
  const float* bk = (const float*)d_in[6];
  const float* Wv = (const float*)d_in[7];
  const float* bv = (const float*)d_in[8];
  const float* Wo = (const float*)d_in[9];
  const float* bo = (const float*)d_in[10];
  float* out = (float*)d_out;

  u16* ws  = (u16*)d_ws;
  u16* Wt  = ws;                                   // 4 x 512*512 (q,k,v,o)
  u16* qws = Wt + 4 * 262144;                      // 8192*512 each
  u16* kws = qws + (size_t)8192 * 512;
  u16* vTw = kws + (size_t)8192 * 512;             // [(b*8+h)*64+d][2048]
  u16* zws = vTw + (size_t)8192 * 512;

  // bf16 copies of Q/K/V in regions dead until later stages:
  // AbfQ/AbfK in d_out (overwritten only by final gemm_out), AbfV in zws
  // (attn writes zws only after qkv finished reading AbfV).
  u16* AbfQ = (u16*)d_out;
  u16* AbfK = AbfQ + (size_t)8192 * 512;
  u16* AbfV = zws;

  prep_k<<<dim3(2048, 7), 256, 0, stream>>>(Wq, Wk, Wv, Wo, Wt, Q, K, V,
                                            AbfQ, AbfK, AbfV);
  qkv_k<<<dim3(256, 3), 256, 0, stream>>>(AbfQ, AbfK, AbfV, Wt, bq, bk, bv, qws);
  attn_k<<<512, 512, 0, stream>>>(qws, kws, vTw, zws);
  gemm_out_k<<<512, 256, 0, stream>>>(zws, Wt + 3 * 262144, bo, out);
}

// Round 23
// 103.939 us; speedup vs baseline: 1.0163x; 1.0163x over previous
//
#include <hip/hip_runtime.h>

// MHA: B=4, S=2048, D_MODEL=512, H=8, D_HEAD=64
// prep (Wt transpose + QKV fp32->bf16) -> qkv GEMMs (gl_lds + XCD swizzle) ->
// flash attn (r23: r21 + V-fragment register prefetch BEFORE softmax (r6 fix:
// sched_barrier then pins only 2 Ps reads, V ds_reads overlap QK^T/softmax)
// + setprio around MFMA clusters) -> out proj GEMM (swizzled).
// r22 lesson: depth-2 prefetch neutral -> residual is intra-tile serialization.

typedef unsigned short u16;
typedef __bf16 bf16x8 __attribute__((ext_vector_type(8)));
typedef float  f32x4  __attribute__((ext_vector_type(4)));

__device__ __forceinline__ u16 f2bf(float x) {
  unsigned u = __float_as_uint(x);
  u += 0x7fffu + ((u >> 16) & 1u);   // RNE
  return (u16)(u >> 16);
}

__device__ __forceinline__ unsigned cvtpk(float lo, float hi) {
  unsigned r;
  asm("v_cvt_pk_bf16_f32 %0, %1, %2" : "=v"(r) : "v"(lo), "v"(hi));
  return r;
}

__device__ __forceinline__ f32x4 mfma16(bf16x8 a, bf16x8 b, f32x4 c) {
  return __builtin_amdgcn_mfma_f32_16x16x32_bf16(a, b, c, 0, 0, 0);
}

// async 16B/lane global->LDS; lds dest is wave-uniform base (HW adds lane*16)
__device__ __forceinline__ void gl16(const u16* g, u16* l) {
  __builtin_amdgcn_global_load_lds(
      (const __attribute__((address_space(1))) void*)g,
      (__attribute__((address_space(3))) void*)l, 16, 0, 0);
}

#define MX3(a, b, c) fmaxf(fmaxf((a), (b)), (c))

// ---- prep: Wt transpose (y=0..3) + Q/K/V fp32->bf16 convert (y=4..6) ----
__global__ __launch_bounds__(256) void prep_k(const float* __restrict__ W0,
                                              const float* __restrict__ W1,
                                              const float* __restrict__ W2,
                                              const float* __restrict__ W3,
                                              u16* __restrict__ Wt,
                                              const float* __restrict__ Q,
                                              const float* __restrict__ K,
                                              const float* __restrict__ V,
                                              u16* __restrict__ Oq,
                                              u16* __restrict__ Ok,
                                              u16* __restrict__ Ov) {
  int y = blockIdx.y;
  if (y < 4) {
    if (blockIdx.x >= 1024) return;
    const float* W = y == 0 ? W0 : y == 1 ? W1 : y == 2 ? W2 : W3;
    int idx = blockIdx.x * 256 + threadIdx.x;
    int k = idx >> 9, n = idx & 511;
    Wt[y * 262144 + n * 512 + k] = f2bf(W[idx]);
  } else {
    int sel = y - 4;
    const float* X = sel == 0 ? Q : sel == 1 ? K : V;
    u16* O = sel == 0 ? Oq : sel == 1 ? Ok : Ov;
    size_t i = ((size_t)blockIdx.x * 256 + threadIdx.x) * 8;
    float4 a = *(const float4*)(X + i);
    float4 b = *(const float4*)(X + i + 4);
    uint4 pk = make_uint4(cvtpk(a.x, a.y), cvtpk(a.z, a.w),
                          cvtpk(b.x, b.y), cvtpk(b.z, b.w));
    *(uint4*)(O + i) = pk;
  }
}

// ---- m97-style bf16 GEMM: A[8192x512] @ Bt^T + bias (Bt [n][k] bf16) ----
// OUT_MODE: 0 bf16 [m][n], 1 bf16 vT[(b*8+h)*64+d][s], 2 fp32 [m][n]
template <int OUT_MODE, int BN>
__device__ __forceinline__ void gemm_body(const u16* __restrict__ A,
                                          const u16* __restrict__ Bt,
                                          const float* __restrict__ bias,
                                          void* __restrict__ outp, int bidx) {
  constexpr int NF = BN / 32;
  constexpr int NBN = 512 / BN;
  __shared__ __align__(16) u16 As[128][64];
  __shared__ __align__(16) u16 Bs[BN][64];
  int tid = threadIdx.x;
  int lane = tid & 63, wid = tid >> 6;
  int wm = wid >> 1, wn = wid & 1;
  int lr = lane & 15, lg = lane >> 4;
  int bm = bidx / NBN, bn = bidx % NBN;

  int r0 = tid >> 3;
  int c8s = (tid & 7) ^ (r0 & 7);
  const u16* Ab = A + (size_t)(bm * 128) * 512;
  const u16* Bb = Bt + (size_t)(bn * BN) * 512;

  f32x4 acc[4][NF];
#pragma unroll
  for (int i = 0; i < 4; ++i)
#pragma unroll
    for (int j = 0; j < NF; ++j) {
      f32x4 z = {0.f, 0.f, 0.f, 0.f};
      acc[i][j] = z;
    }

#pragma unroll
  for (int kt = 0; kt < 8; ++kt) {
    int k0 = kt * 64;
#pragma unroll
    for (int i = 0; i < 4; ++i)
      gl16(&Ab[(size_t)(i * 32 + r0) * 512 + k0 + c8s * 8],
           &As[0][0] + i * 2048 + wid * 512);
#pragma unroll
    for (int i = 0; i < BN / 32; ++i)
      gl16(&Bb[(size_t)(i * 32 + r0) * 512 + k0 + c8s * 8],
           &Bs[0][0] + i * 2048 + wid * 512);
    __syncthreads();
#pragma unroll
    for (int kk = 0; kk < 2; ++kk) {
      bf16x8 af[4], bfr[NF];
      int sw = (lr & 7) << 3;
#pragma unroll
      for (int mf = 0; mf < 4; ++mf)
        af[mf] = *(const bf16x8*)&As[wm * 64 + mf * 16 + lr][(kk * 32 + lg * 8) ^ sw];
#pragma unroll
      for (int nf = 0; nf < NF; ++nf)
        bfr[nf] = *(const bf16x8*)&Bs[wn * (BN / 2) + nf * 16 + lr][(kk * 32 + lg * 8) ^ sw];
#pragma unroll
      for (int mf = 0; mf < 4; ++mf)
#pragma unroll
        for (int nf = 0; nf < NF; ++nf)
          acc[mf][nf] = mfma16(af[mf], bfr[nf], acc[mf][nf]);
    }
    __syncthreads();
  }

#pragma unroll
  for (int mf = 0; mf < 4; ++mf) {
#pragma unroll
    for (int nf = 0; nf < NF; ++nf) {
      int m = bm * 128 + wm * 64 + mf * 16 + lg * 4;
      int n = bn * BN + wn * (BN / 2) + nf * 16 + lr;
      float bia = bias[n];
      if (OUT_MODE == 0) {
        u16* o = (u16*)outp;
#pragma unroll
        for (int r = 0; r < 4; ++r)
          o[(size_t)(m + r) * 512 + n] = f2bf(acc[mf][nf][r] + bia);
      } else if (OUT_MODE == 2) {
        float* o = (float*)outp;
#pragma unroll
        for (int r = 0; r < 4; ++r)
          o[(size_t)(m + r) * 512 + n] = acc[mf][nf][r] + bia;
      } else {
        u16* o = (u16*)outp;
        int b = m >> 11, s = m & 2047;
        int h = n >> 6, d = n & 63;
        ushort4 pk = make_ushort4(f2bf(acc[mf][nf][0] + bia), f2bf(acc[mf][nf][1] + bia),
                                  f2bf(acc[mf][nf][2] + bia), f2bf(acc[mf][nf][3] + bia));
        *(ushort4*)&o[(size_t)((b * 8 + h) * 64 + d) * 2048 + s] = pk;
      }
    }
  }
}

__global__ __launch_bounds__(256) void qkv_k(const u16* __restrict__ Aq,
                                             const u16* __restrict__ Ak,
                                             const u16* __restrict__ Av,
                                             const u16* __restrict__ Wt,
                                             const float* __restrict__ bq,
                                             const float* __restrict__ bk,
                                             const float* __restrict__ bv,
                                             u16* __restrict__ outbase) {
  int sel = blockIdx.y;
  const u16* A = sel == 0 ? Aq : sel == 1 ? Ak : Av;
  const float* bia = sel == 0 ? bq : sel == 1 ? bk : bv;
  const u16* Bt = Wt + (size_t)sel * 262144;
  u16* out = outbase + (size_t)sel * 8192 * 512;
  int wg = blockIdx.x;
  int wgs = (wg & 7) * 32 + (wg >> 3);   // XCD swizzle (bijective)
  if (sel == 2)
    gemm_body<1, 128>(A, Bt, bia, out, wgs);
  else
    gemm_body<0, 128>(A, Bt, bia, out, wgs);
}

__global__ __launch_bounds__(256) void gemm_out_k(const u16* __restrict__ Ap,
                                                  const u16* __restrict__ Bt,
                                                  const float* __restrict__ bias,
                                                  void* __restrict__ outp) {
  int wg = blockIdx.x;
  int wgs = (wg & 7) * 64 + (wg >> 3);   // XCD swizzle (bijective)
  gemm_body<2, 64>(Ap, Bt, bias, outp, wgs);
}

// ---- flash attention r23: r21 + V-reg prefetch + setprio ----
// 8 waves/block, QBLK=128, K[2]/V[2] gl_lds dbuf, XCD swizzle, 1 barrier/tile.
__global__ __launch_bounds__(512) void attn_k(const u16* __restrict__ q,
                                              const u16* __restrict__ kmat,
                                              const u16* __restrict__ vT,
                                              u16* __restrict__ z) {
  __shared__ __align__(16) u16 Ks[2][64][64];   // [buf][key][d], swizzled content
  __shared__ __align__(16) u16 Vs[2][64][64];   // [buf][d][key], swizzled content
  __shared__ __align__(16) u16 Ps[8][16][72];   // per-wave P[q][key]
  const float C = 0.125f * 1.44269504f;         // 1/sqrt(64) * log2(e)
  int tid = threadIdx.x;
  int lane = tid & 63, w = tid >> 6;            // w = 0..7
  int lr = lane & 15, lg = lane >> 4;
  // XCD swizzle (bijective, 512 % 8 == 0): XCD x owns 4 consecutive bh.
  int wg = blockIdx.x;
  int wgs = (wg & 7) * 64 + (wg >> 3);
  int bh = wgs >> 4, qt = wgs & 15;
  int b = bh >> 3, h = bh & 7;
  size_t qrow0 = (size_t)(b * 2048 + qt * 128 + w * 16);

  bf16x8 qf[2];
#pragma unroll
  for (int kf = 0; kf < 2; ++kf)
    qf[kf] = *(const bf16x8*)&q[(qrow0 + lr) * 512 + h * 64 + kf * 32 + lg * 8];

  f32x4 oacc[4];
#pragma unroll
  for (int j = 0; j < 4; ++j) {
    f32x4 zf = {0.f, 0.f, 0.f, 0.f};
    oacc[j] = zf;
  }
  float m = -1e30f, l_part = 0.f, negmC = 0.f;

  const u16* kbase = kmat + (size_t)(b * 2048) * 512 + h * 64;
  const u16* vbase = vT + (size_t)(bh * 64) * 2048;

  int r0 = tid >> 3;                         // 0..63 (512 threads cover 64 rows)
  int c8s = (tid & 7) ^ (r0 & 7);
  int sw = (lr & 7) << 3;                    // fragment-read swizzle (row&7 == lr&7)
  // prologue: K(0),V(0) -> buf0
  gl16(&kbase[(size_t)r0 * 512 + c8s * 8], &Ks[0][0][0] + w * 512);
  gl16(&vbase[(size_t)r0 * 2048 + c8s * 8], &Vs[0][0][0] + w * 512);
  asm volatile("s_waitcnt vmcnt(0)" ::: "memory");
  __syncthreads();

  // one KV tile; cur buffers passed as literal pointers per call site
  auto tile = [&](int kt, const u16* Kc, u16* Kn, const u16* Vc, u16* Vn) {
    // issue K(kt+1), V(kt+1) into the buffers freed at last tile's barrier
    if (kt < 31) {
      gl16(&kbase[(size_t)((kt + 1) * 64 + r0) * 512 + c8s * 8], Kn + w * 512);
      gl16(&vbase[(size_t)r0 * 2048 + (kt + 1) * 64 + c8s * 8], Vn + w * 512);
    }

    // S^T = K @ Q^T : sacc[nf][r] = S[q=lr][key = nf*16 + lg*4 + r]
    f32x4 sacc[4];
#pragma unroll
    for (int j = 0; j < 4; ++j) {
      f32x4 zf = {0.f, 0.f, 0.f, 0.f};
      sacc[j] = zf;
    }
    __builtin_amdgcn_s_setprio(1);
#pragma unroll
    for (int kf = 0; kf < 2; ++kf) {
#pragma unroll
      for (int nf = 0; nf < 4; ++nf) {
        int row = nf * 16 + lr;
        bf16x8 kb = *(const bf16x8*)&Kc[row * 64 + ((kf * 32 + lg * 8) ^ sw)];
        sacc[nf] = mfma16(kb, qf[kf], sacc[nf]);
      }
    }
    __builtin_amdgcn_s_setprio(0);

    // V-fragment prefetch to registers (r6 fix): V(kt) resident since last
    // barrier; issuing these BEFORE the softmax lets the 8 ds_reads overlap
    // the VALU chain -- the sched_barrier below then pins only 2 Ps reads.
    bf16x8 vb[2][4];
#pragma unroll
    for (int ks = 0; ks < 2; ++ks)
#pragma unroll
      for (int nfo = 0; nfo < 4; ++nfo) {
        int row = nfo * 16 + lr;
        vb[ks][nfo] = *(const bf16x8*)&Vc[row * 64 + ((ks * 32 + lg * 8) ^ sw)];
      }

    // lane-local 16-value max via max3 triples (8 ops)
    float t0 = MX3(sacc[0][0], sacc[0][1], sacc[0][2]);
    float t1 = MX3(sacc[0][3], sacc[1][0], sacc[1][1]);
    float t2 = MX3(sacc[1][2], sacc[1][3], sacc[2][0]);
    float t3 = MX3(sacc[2][1], sacc[2][2], sacc[2][3]);
    float t4 = MX3(sacc[3][0], sacc[3][1], sacc[3][2]);
    float mxl = fmaxf(MX3(t0, t1, t2), MX3(t3, t4, sacc[3][3]));

    // defer-max: lane-local test exact; shuffles + rescale only in rare branch
    if (!__all(mxl - m <= 8.f)) {
      float mx = fmaxf(mxl, __shfl_xor(mxl, 16));
      mx = fmaxf(mx, __shfl_xor(mx, 32));
      float mnew = fmaxf(m, mx);
      float sc = __builtin_amdgcn_exp2f((m - mnew) * C);
      m = mnew;
      negmC = -m * C;
      l_part *= sc;
#pragma unroll
      for (int nfo = 0; nfo < 4; ++nfo)
#pragma unroll
        for (int r = 0; r < 4; ++r) oacc[nfo][r] *= sc;
    }

    // P = exp2(S*C - m*C); per-lane partial sum; pack to Ps
    float rsum = 0.f;
#pragma unroll
    for (int nf = 0; nf < 4; ++nf) {
      float p0 = __builtin_amdgcn_exp2f(fmaf(sacc[nf][0], C, negmC));
      float p1 = __builtin_amdgcn_exp2f(fmaf(sacc[nf][1], C, negmC));
      float p2 = __builtin_amdgcn_exp2f(fmaf(sacc[nf][2], C, negmC));
      float p3 = __builtin_amdgcn_exp2f(fmaf(sacc[nf][3], C, negmC));
      rsum += (p0 + p1) + (p2 + p3);
      uint2 pw = make_uint2(cvtpk(p0, p1), cvtpk(p2, p3));
      *(uint2*)&Ps[w][lr][nf * 16 + lg * 4] = pw;
    }
    l_part += rsum;

    // Ps write->read ordering (wave-private): proven fence pair.
    // Pinned region = 2 Ps reads + 8 MFMAs (V already in registers).
    asm volatile("s_waitcnt lgkmcnt(0)" ::: "memory");
    __builtin_amdgcn_sched_barrier(0);

    // O^T += V^T @ P^T
    __builtin_amdgcn_s_setprio(1);
#pragma unroll
    for (int ks = 0; ks < 2; ++ks) {
      bf16x8 pa = *(const bf16x8*)&Ps[w][lr][ks * 32 + lg * 8];
#pragma unroll
      for (int nfo = 0; nfo < 4; ++nfo)
        oacc[nfo] = mfma16(vb[ks][nfo], pa, oacc[nfo]);
    }
    __builtin_amdgcn_s_setprio(0);

    // single end-of-tile barrier: drains K(kt+1)+V(kt+1) (vmcnt 0) and
    // synchronizes buffer reuse; order-robust (full drain).
    asm volatile("s_waitcnt vmcnt(0)" ::: "memory");
    __syncthreads();
  };

  for (int ko = 0; ko < 32; ko += 2) {
    tile(ko,     &Ks[0][0][0], &Ks[1][0][0], &Vs[0][0][0], &Vs[1][0][0]);
    tile(ko + 1, &Ks[1][0][0], &Ks[0][0][0], &Vs[1][0][0], &Vs[0][0][0]);
  }

  // combine per-lane l partials once (row = lanes {lr, lr+16, lr+32, lr+48})
  float l = l_part + __shfl_xor(l_part, 16);
  l += __shfl_xor(l, 32);
  float rl = 1.f / l;
#pragma unroll
  for (int nfo = 0; nfo < 4; ++nfo) {
    uint2 pw = make_uint2(cvtpk(oacc[nfo][0] * rl, oacc[nfo][1] * rl),
                          cvtpk(oacc[nfo][2] * rl, oacc[nfo][3] * rl));
    *(uint2*)&z[(qrow0 + lr) * 512 + h * 64 + nfo * 16 + lg * 4] = pw;
  }
}

extern "C" void kernel_launch(void* const* d_in, const int* in_sizes, int n_in,
                              void* d_out, int out_size, void* d_ws, size_t ws_size,
                              hipStream_t stream) {
  const float* Q  = (const float*)d_in[0];
  const float* K  = (const float*)d_in[1];
  const float* V  = (const float*)d_in[2];
  const float* Wq = (const float*)d_in[3];
  const float* bq = (const float*)d_in[4];
  const float* Wk = (const float*)d_in[5];
  const float* bk = (const float*)d_in[6];
  const float* Wv = (const float*)d_in[7];
  const float* bv = (const float*)d_in[8];
  const float* Wo = (const float*)d_in[9];
  const float* bo = (const float*)d_in[10];
  float* out = (float*)d_out;

  u16* ws  = (u16*)d_ws;
  u16* Wt  = ws;                                   // 4 x 512*512 (q,k,v,o)
  u16* qws = Wt + 4 * 262144;                      // 8192*512 each
  u16* kws = qws + (size_t)8192 * 512;
  u16* vTw = kws + (size_t)8192 * 512;             // [(b*8+h)*64+d][2048]
  u16* zws = vTw + (size_t)8192 * 512;

  // bf16 copies of Q/K/V in regions dead until later stages:
  // AbfQ/AbfK in d_out (overwritten only by final gemm_out), AbfV in zws
  // (attn writes zws only after qkv finished reading AbfV).
  u16* AbfQ = (u16*)d_out;
  u16* AbfK = AbfQ + (size_t)8192 * 512;
  u16* AbfV = zws;

  prep_k<<<dim3(2048, 7), 256, 0, stream>>>(Wq, Wk, Wv, Wo, Wt, Q, K, V,
                                            AbfQ, AbfK, AbfV);
  qkv_k<<<dim3(256, 3), 256, 0, stream>>>(AbfQ, AbfK, AbfV, Wt, bq, bk, bv, qws);
  attn_k<<<512, 512, 0, stream>>>(qws, kws, vTw, zws);
  gemm_out_k<<<512, 256, 0, stream>>>(zws, Wt + 3 * 262144, bo, out);
}